// Round 1
// baseline (236.175 us; speedup 1.0000x reference)
//
#include <hip/hip_runtime.h>
#include <math.h>

#define B_ 32
#define C_ 3
#define H_ 256
#define W_ 256
#define HW_ 65536
#define CHW_ 196608
#define TOT_ 6291456

// ---- ws layout (bytes) ----
#define VIEWS_OFF_B 0ull
#define HIST_OFF_B  (4ull * TOT_ * 4ull)            // 4 views of f32
#define STATE_OFF_B (HIST_OFF_B + 32ull*2048*4)     // 32 x {prefix, krem}
#define SCALE_OFF_B (STATE_OFF_B + 32ull*8)
#define PMAD_OFF_B  (SCALE_OFF_B + 32ull*4)
#define PDEV_OFF_B  (PMAD_OFF_B + 1536ull*4)
#define MEAN_OFF_B  (PDEV_OFF_B + 1536ull*4)

// ---- tile geometry for TV views ----
#define TS 72        // 64 + 2*4 halo
#define NPR 36       // pairs per row
#define NPAIRS 2592  // 72*36
#define NCELLS 5184  // 72*72

__device__ __forceinline__ float g_of(float d, float delta) {
    return d * __builtin_amdgcn_rcpf(delta + fabsf(d));
}

__device__ __forceinline__ void cswap(float& a, float& b) {
    float lo = fminf(a, b), hi = fmaxf(a, b); a = lo; b = hi;
}
__device__ __forceinline__ float median5(float a0, float a1, float a2, float a3, float a4) {
    cswap(a0,a1); cswap(a3,a4); cswap(a2,a4); cswap(a2,a3); cswap(a0,a3);
    cswap(a0,a2); cswap(a1,a4); cswap(a1,a3); cswap(a1,a2);
    return a2;
}

// ---------------- K1: radix-select median of |x| per sample ----------------
__global__ void k_init(unsigned* state) {
    int t = threadIdx.x;
    if (t < 32) { state[2*t] = 0u; state[2*t+1] = 98303u; }  // (196608-1)//2
}

__global__ __launch_bounds__(256) void k_hist(const float* __restrict__ x,
                                              unsigned* __restrict__ ghist,
                                              const unsigned* __restrict__ state,
                                              unsigned matchmask, int shift) {
    __shared__ unsigned h[2048];
    int t = threadIdx.x, chunk = blockIdx.x, s = blockIdx.y;
    #pragma unroll
    for (int i = 0; i < 8; i++) h[t + 256*i] = 0u;
    __syncthreads();
    unsigned prefix = state[2*s];
    size_t base = (size_t)s*CHW_ + (size_t)chunk*4096;
    #pragma unroll
    for (int i = 0; i < 16; i++) {
        float v = x[base + i*256 + t];
        unsigned u = __float_as_uint(fabsf(v));
        if ((u & matchmask) == prefix) atomicAdd(&h[(u >> shift) & 2047u], 1u);
    }
    __syncthreads();
    #pragma unroll
    for (int i = 0; i < 8; i++) {
        unsigned c = h[t + 256*i];
        if (c) atomicAdd(&ghist[s*2048 + t + 256*i], c);
    }
}

__global__ __launch_bounds__(256) void k_select(unsigned* __restrict__ ghist,
                                                unsigned* __restrict__ state,
                                                float* __restrict__ scale,
                                                int shift, int final_pass) {
    __shared__ unsigned sc[256];
    int t = threadIdx.x, s = blockIdx.x;
    unsigned krem = state[2*s+1];
    unsigned v[8]; unsigned ts = 0;
    #pragma unroll
    for (int i = 0; i < 8; i++) { v[i] = ghist[s*2048 + t*8 + i]; ts += v[i]; }
    sc[t] = ts; __syncthreads();
    for (int off = 1; off < 256; off <<= 1) {
        unsigned a = sc[t];
        unsigned b = (t >= off) ? sc[t-off] : 0u;
        __syncthreads();
        sc[t] = a + b;
        __syncthreads();
    }
    unsigned incl = sc[t], base = incl - ts;
    if (ts > 0 && base <= krem && krem < incl) {
        unsigned c = base; int dig = -1; unsigned nk = 0;
        #pragma unroll
        for (int i = 0; i < 8; i++) {
            if (dig < 0) {
                if (krem < c + v[i]) { dig = t*8 + i; nk = krem - c; }
                else c += v[i];
            }
        }
        unsigned prefix = state[2*s] | ((unsigned)dig << shift);
        state[2*s] = prefix;
        state[2*s+1] = nk;
        if (final_pass) scale[s] = __uint_as_float(prefix) + 1e-8f;
    }
    #pragma unroll
    for (int i = 0; i < 8; i++) ghist[s*2048 + t*8 + i] = 0u;
}

// ---------------- K2: 4 Huber-TV views, 3 iterations fused per tile ----------------
__global__ __launch_bounds__(256) void k_views(const float* __restrict__ x,
        float* __restrict__ views, const float* __restrict__ scale,
        float l0, float l1, float l2, float l3,
        float e0, float e1, float e2, float e3) {
    __shared__ float xn_s[NCELLS];
    __shared__ float xd_s[NCELLS];
    const int t = threadIdx.x;
    const int tile = blockIdx.x;
    const int bc = blockIdx.y;
    const int b = bc / 3;
    const int i0 = (tile >> 2) * 64, j0 = (tile & 3) * 64;
    const float sc = scale[b];
    const float* img = x + (size_t)bc * HW_;

    // load extended tile, normalized (exact IEEE division to match reference)
    #pragma unroll
    for (int k = 0; k < 21; k++) {
        int p = t + 256*k;
        if (p < NCELLS) {
            int u = p / TS, v = p - u*TS;
            int gi = i0 - 4 + u, gj = j0 - 4 + v;
            float val = 0.f;
            if (gi >= 0 && gi < H_ && gj >= 0 && gj < W_) val = img[gi*W_ + gj] / sc;
            xn_s[p] = val;
        }
    }
    __syncthreads();

    // per-thread pair ownership (pairs strided by 256)
    int ua[11], va[11];
    float xn0[11], xn1[11];
    #pragma unroll
    for (int k = 0; k < 11; k++) {
        int p = t + 256*k;
        int u = 0, v0 = 0;
        if (p < NPAIRS) { u = p / NPR; v0 = 2*(p - u*NPR); }
        ua[k] = u; va[k] = v0;
        if (p < NPAIRS) { xn0[k] = xn_s[u*TS + v0]; xn1[k] = xn_s[u*TS + v0 + 1]; }
        else            { xn0[k] = 0.f; xn1[k] = 0.f; }
    }

    float c0[11], c1[11], n0[11], n1[11];

    #pragma unroll 1
    for (int view = 0; view < 4; view++) {
        const float lam = (view==0)?l0:(view==1)?l1:(view==2)?l2:l3;
        const float del = (view==0)?e0:(view==1)?e1:(view==2)?e2:e3;
        #pragma unroll
        for (int k = 0; k < 11; k++) { c0[k] = xn0[k]; c1[k] = xn1[k]; }

        #pragma unroll 1
        for (int it = 0; it < 3; it++) {
            const float* src = (it == 0) ? xn_s : xd_s;
            #pragma unroll
            for (int k = 0; k < 11; k++) {
                int p = t + 256*k;
                if (p >= NPAIRS) { n0[k] = 0.f; n1[k] = 0.f; continue; }
                int u = ua[k], v0 = va[k];
                int gi = i0 - 4 + u, gj0 = j0 - 4 + v0, gj1 = gj0 + 1;
                float a0 = c0[k], a1 = c1[k];
                int vm = (v0 > 0) ? v0 - 1 : 0;
                int vp = (v0 + 2 < TS) ? v0 + 2 : TS - 1;
                int um = (u > 0) ? u - 1 : 0;
                int ud = (u + 1 < TS) ? u + 1 : TS - 1;
                int bi = u*TS + v0;
                float lft = src[u*TS + vm];
                float rgt = src[u*TS + vp];
                float up0 = src[um*TS + v0], up1 = src[um*TS + v0 + 1];
                float dn0 = src[ud*TS + v0], dn1 = src[ud*TS + v0 + 1];
                (void)bi;
                float m    = g_of(a1 - a0, del);
                float gxl0 = (gj0 > 0)      ? g_of(a0 - lft, del) : 0.f;
                float gxr0 = (gj0 < W_ - 1) ? m : 0.f;
                float gxl1 = (gj1 > 0)      ? m : 0.f;
                float gxr1 = (gj1 < W_ - 1) ? g_of(rgt - a1, del) : 0.f;
                float gyu0 = (gi > 0)       ? g_of(a0 - up0, del) : 0.f;
                float gyd0 = (gi < H_ - 1)  ? g_of(dn0 - a0, del) : 0.f;
                float gyu1 = (gi > 0)       ? g_of(a1 - up1, del) : 0.f;
                float gyd1 = (gi < H_ - 1)  ? g_of(dn1 - a1, del) : 0.f;
                float dv0 = (gxr0 - gxl0) + (gyd0 - gyu0);
                float dv1 = (gxr1 - gxl1) + (gyd1 - gyu1);
                float r0 = a0 - 0.2f * (a0 - xn0[k] - lam * dv0);
                float r1 = a1 - 0.2f * (a1 - xn1[k] - lam * dv1);
                bool in0 = (gi >= 0) && (gi < H_) && (gj0 >= 0) && (gj0 < W_);
                bool in1 = (gi >= 0) && (gi < H_) && (gj1 >= 0) && (gj1 < W_);
                n0[k] = in0 ? r0 : 0.f;
                n1[k] = in1 ? r1 : 0.f;
            }
            if (it < 2) {
                __syncthreads();   // all snapshot reads done (also fences prev view's last reads)
                #pragma unroll
                for (int k = 0; k < 11; k++) {
                    int p = t + 256*k;
                    if (p < NPAIRS) {
                        int bi = ua[k]*TS + va[k];
                        xd_s[bi] = n0[k]; xd_s[bi+1] = n1[k];
                    }
                    c0[k] = n0[k]; c1[k] = n1[k];
                }
                __syncthreads();
            }
        }
        // store center 64x64 (iteration-3 results live in n0/n1)
        float* vout = views + (size_t)view * TOT_ + (size_t)bc * HW_;
        #pragma unroll
        for (int k = 0; k < 11; k++) {
            int p = t + 256*k;
            if (p >= NPAIRS) continue;
            int u = ua[k], v0 = va[k];
            if (u >= 4 && u < 68 && v0 >= 4 && v0 < 68) {
                int gi = i0 - 4 + u, gj = j0 - 4 + v0;
                float2 o; o.x = n0[k] * sc; o.y = n1[k] * sc;
                *reinterpret_cast<float2*>(&vout[gi*W_ + gj]) = o;
            }
        }
    }
}

// ---------------- K3: per-pixel med/dev/mad -> deterministic partials ----------------
__global__ __launch_bounds__(256) void k_stats(const float* __restrict__ x,
                                               const float* __restrict__ views,
                                               float* __restrict__ pmad,
                                               float* __restrict__ pdev) {
    int t = threadIdx.x, chunk = blockIdx.x, b = blockIdx.y;
    size_t base = (size_t)b*CHW_ + (size_t)chunk*4096;
    float am = 0.f, ad = 0.f;
    for (int i = 0; i < 16; i++) {
        size_t idx = base + i*256 + t;
        float s0 = x[idx];
        float s1 = views[idx];
        float s2 = views[(size_t)TOT_ + idx];
        float s3 = views[2ull*TOT_ + idx];
        float s4 = views[3ull*TOT_ + idx];
        float med = median5(s0, s1, s2, s3, s4);
        float d0 = fabsf(s0-med), d1 = fabsf(s1-med), d2 = fabsf(s2-med),
              d3 = fabsf(s3-med), d4 = fabsf(s4-med);
        float mad = median5(d0, d1, d2, d3, d4);
        am += mad;
        ad += d0 + d1 + d2 + d3 + d4;
    }
    __shared__ float r[256];
    r[t] = am; __syncthreads();
    for (int off = 128; off > 0; off >>= 1) { if (t < off) r[t] += r[t+off]; __syncthreads(); }
    if (t == 0) pmad[b*48 + chunk] = r[0];
    __syncthreads();
    r[t] = ad; __syncthreads();
    for (int off = 128; off > 0; off >>= 1) { if (t < off) r[t] += r[t+off]; __syncthreads(); }
    if (t == 0) pdev[b*48 + chunk] = r[0];
}

// ---------------- K4: finalize scalars (mad mean, beta) ----------------
__global__ __launch_bounds__(256) void k_final(const float* __restrict__ pmad,
                                               const float* __restrict__ pdev,
                                               float* __restrict__ meanp,
                                               float* __restrict__ out_beta) {
    __shared__ float r[256];
    int t = threadIdx.x;
    float s = 0.f;
    for (int j = t; j < 1536; j += 256) s += pmad[j];
    r[t] = s; __syncthreads();
    for (int off = 128; off > 0; off >>= 1) { if (t < off) r[t] += r[t+off]; __syncthreads(); }
    if (t == 0) meanp[0] = r[0] / (float)TOT_;
    if (t < 32) {
        float sd = 0.f;
        for (int j = 0; j < 48; j++) sd += pdev[t*48 + j];
        float D = sd / (5.0f * (float)CHW_);
        float z = (D - 0.02f) / 0.01f;
        out_beta[t] = 1.0f / (1.0f + __expf(-z));
    }
}

// ---------------- K5: fusion ----------------
__global__ __launch_bounds__(256) void k_fuse(const float* __restrict__ x,
                                              const float* __restrict__ views,
                                              const float* __restrict__ meanp,
                                              float* __restrict__ out) {
    int t = threadIdx.x;
    size_t base = (size_t)blockIdx.x * 4096;
    float floorv = 0.1f * meanp[0];
    for (int i = 0; i < 16; i++) {
        size_t idx = base + i*256 + t;
        float s0 = x[idx];
        float s1 = views[idx];
        float s2 = views[(size_t)TOT_ + idx];
        float s3 = views[2ull*TOT_ + idx];
        float s4 = views[3ull*TOT_ + idx];
        float med = median5(s0, s1, s2, s3, s4);
        float d0 = fabsf(s0-med), d1 = fabsf(s1-med), d2 = fabsf(s2-med),
              d3 = fabsf(s3-med), d4 = fabsf(s4-med);
        float mad = median5(d0, d1, d2, d3, d4);
        float madf = fmaxf(mad, floorv);
        float inv = 1.0f / (2.0f * madf);
        float w0 = __expf(-d0*inv), w1 = __expf(-d1*inv), w2 = __expf(-d2*inv),
              w3 = __expf(-d3*inv), w4 = __expf(-d4*inv);
        float num = w0*s0 + w1*s1 + w2*s2 + w3*s3 + w4*s4;
        float den = w0 + w1 + w2 + w3 + w4 + 1e-8f;
        out[idx] = num / den;
    }
}

extern "C" void kernel_launch(void* const* d_in, const int* in_sizes, int n_in,
                              void* d_out, int out_size, void* d_ws, size_t ws_size,
                              hipStream_t stream) {
    const float* x = (const float*)d_in[0];
    float* out = (float*)d_out;
    char* ws = (char*)d_ws;
    float*    views = (float*)(ws + VIEWS_OFF_B);
    unsigned* ghist = (unsigned*)(ws + HIST_OFF_B);
    unsigned* state = (unsigned*)(ws + STATE_OFF_B);
    float*    scale = (float*)(ws + SCALE_OFF_B);
    float*    pmad  = (float*)(ws + PMAD_OFF_B);
    float*    pdev  = (float*)(ws + PDEV_OFF_B);
    float*    meanp = (float*)(ws + MEAN_OFF_B);

    // param sets: replicate np.random.RandomState(0).uniform(-.1,.1) draws
    const double s4[4] = {0.5488135039273248, 0.7151893663724195,
                          0.6027633760716439, 0.5448831829968969};
    float lam[4], del[4];
    for (int i = 0; i < 4; i++) {
        double lb  = 0.025 + (0.075 - 0.025) * (double)i / 3.0;
        double jit = -0.1 + 0.2 * s4[i];
        double li  = lb * (1.0 + jit);
        if (li < 0.0) li = 0.0;
        double di  = 0.01 * sqrt(li / (0.05 + 1e-8));
        lam[i] = (float)li; del[i] = (float)di;
    }

    hipMemsetAsync(ghist, 0, 32*2048*4, stream);
    k_init<<<1, 32, 0, stream>>>(state);

    // 3-pass radix select: bits [31:21], [20:10], [10:0]
    k_hist  <<<dim3(48,32), 256, 0, stream>>>(x, ghist, state, 0u,          21);
    k_select<<<32,          256, 0, stream>>>(ghist, state, scale, 21, 0);
    k_hist  <<<dim3(48,32), 256, 0, stream>>>(x, ghist, state, 0xFFE00000u, 10);
    k_select<<<32,          256, 0, stream>>>(ghist, state, scale, 10, 0);
    k_hist  <<<dim3(48,32), 256, 0, stream>>>(x, ghist, state, 0xFFFFFC00u, 0);
    k_select<<<32,          256, 0, stream>>>(ghist, state, scale, 0, 1);

    k_views<<<dim3(16,96), 256, 0, stream>>>(x, views, scale,
                                             lam[0], lam[1], lam[2], lam[3],
                                             del[0], del[1], del[2], del[3]);
    k_stats<<<dim3(48,32), 256, 0, stream>>>(x, views, pmad, pdev);
    k_final<<<1,           256, 0, stream>>>(pmad, pdev, meanp, out + TOT_);
    k_fuse <<<1536,        256, 0, stream>>>(x, views, meanp, out);
    (void)in_sizes; (void)n_in; (void)out_size; (void)ws_size;
}

// Round 2
// 173.891 us; speedup vs baseline: 1.3582x; 1.3582x over previous
//
#include <hip/hip_runtime.h>
#include <math.h>

#define B_ 32
#define C_ 3
#define H_ 256
#define W_ 256
#define HW_ 65536
#define CHW_ 196608
#define TOT_ 6291456

// ---- ws layout (bytes) ----
#define VIEWS_OFF_B 0ull
#define HIST_OFF_B  (4ull * TOT_ * 4ull)            // 4 views of f32
#define STATE_OFF_B (HIST_OFF_B + 32ull*2048*4)     // 32 x {prefix, krem}
#define SCALE_OFF_B (STATE_OFF_B + 32ull*8)
#define PMAD_OFF_B  (SCALE_OFF_B + 32ull*4)
#define PDEV_OFF_B  (PMAD_OFF_B + 1536ull*4)
#define MEAN_OFF_B  (PDEV_OFF_B + 1536ull*4)

// ---- tile geometry for TV views ----
#define TSB 72       // row width: 64 + 2*4 halo
#define ROWSB 74     // 1 guard + 72 + 1 guard
#define NB (ROWSB*TSB)   // 5328 cells
#define NPR 36       // pairs per row
#define NPAIRS 2592  // 72*36

__device__ __forceinline__ float g_of(float d, float delta) {
    return d * __builtin_amdgcn_rcpf(delta + fabsf(d));
}

__device__ __forceinline__ void cswap(float& a, float& b) {
    float lo = fminf(a, b), hi = fmaxf(a, b); a = lo; b = hi;
}
__device__ __forceinline__ float median5(float a0, float a1, float a2, float a3, float a4) {
    cswap(a0,a1); cswap(a3,a4); cswap(a2,a4); cswap(a2,a3); cswap(a0,a3);
    cswap(a0,a2); cswap(a1,a4); cswap(a1,a3); cswap(a1,a2);
    return a2;
}

// ---------------- K1: radix-select median of |x| per sample ----------------
__global__ void k_init(unsigned* state) {
    int t = threadIdx.x;
    if (t < 32) { state[2*t] = 0u; state[2*t+1] = 98303u; }  // (196608-1)//2
}

__global__ __launch_bounds__(256) void k_hist(const float* __restrict__ x,
                                              unsigned* __restrict__ ghist,
                                              const unsigned* __restrict__ state,
                                              unsigned matchmask, int shift) {
    __shared__ unsigned h[2048];
    int t = threadIdx.x, chunk = blockIdx.x, s = blockIdx.y;
    #pragma unroll
    for (int i = 0; i < 8; i++) h[t + 256*i] = 0u;
    __syncthreads();
    unsigned prefix = state[2*s];
    size_t base = (size_t)s*CHW_ + (size_t)chunk*4096;
    #pragma unroll
    for (int i = 0; i < 16; i++) {
        float v = x[base + i*256 + t];
        unsigned u = __float_as_uint(fabsf(v));
        if ((u & matchmask) == prefix) atomicAdd(&h[(u >> shift) & 2047u], 1u);
    }
    __syncthreads();
    #pragma unroll
    for (int i = 0; i < 8; i++) {
        unsigned c = h[t + 256*i];
        if (c) atomicAdd(&ghist[s*2048 + t + 256*i], c);
    }
}

__global__ __launch_bounds__(256) void k_select(unsigned* __restrict__ ghist,
                                                unsigned* __restrict__ state,
                                                float* __restrict__ scale,
                                                int shift, int final_pass) {
    __shared__ unsigned sc[256];
    int t = threadIdx.x, s = blockIdx.x;
    unsigned krem = state[2*s+1];
    unsigned v[8]; unsigned ts = 0;
    #pragma unroll
    for (int i = 0; i < 8; i++) { v[i] = ghist[s*2048 + t*8 + i]; ts += v[i]; }
    sc[t] = ts; __syncthreads();
    for (int off = 1; off < 256; off <<= 1) {
        unsigned a = sc[t];
        unsigned b = (t >= off) ? sc[t-off] : 0u;
        __syncthreads();
        sc[t] = a + b;
        __syncthreads();
    }
    unsigned incl = sc[t], base = incl - ts;
    if (ts > 0 && base <= krem && krem < incl) {
        unsigned c = base; int dig = -1; unsigned nk = 0;
        #pragma unroll
        for (int i = 0; i < 8; i++) {
            if (dig < 0) {
                if (krem < c + v[i]) { dig = t*8 + i; nk = krem - c; }
                else c += v[i];
            }
        }
        unsigned prefix = state[2*s] | ((unsigned)dig << shift);
        state[2*s] = prefix;
        state[2*s+1] = nk;
        if (final_pass) scale[s] = __uint_as_float(prefix) + 1e-8f;
    }
    #pragma unroll
    for (int i = 0; i < 8; i++) ghist[s*2048 + t*8 + i] = 0u;
}

// ---------------- K2: 4 Huber-TV views, 3 iterations, single-buffer ----------------
// Boundary handling: out-of-image distance-1 halo cells are kept equal to the
// current edge value ("mirror writes") so every cross-boundary gradient is
// g(0)=0 == reference's masked zero. Inner loop is fully unconditional.
__global__ __launch_bounds__(256, 4) void k_views(const float* __restrict__ x,
        float* __restrict__ views, const float* __restrict__ scale,
        float l0, float l1, float l2, float l3,
        float e0, float e1, float e2, float e3) {
    __shared__ float Bf[NB];
    const int t = threadIdx.x;
    const int tile = blockIdx.x, bc = blockIdx.y, b = bc / 3;
    const int i0 = (tile >> 2) * 64, j0 = (tile & 3) * 64;
    const float sc = scale[b];
    const float* img = x + (size_t)bc * HW_;

    // load full buffer incl guard rows, clamp-replicated, normalized (exact IEEE div)
    for (int p = t; p < NB; p += 256) {
        int u = p / TSB, v = p - u * TSB;
        int gi = i0 - 5 + u; gi = gi < 0 ? 0 : (gi > 255 ? 255 : gi);
        int gj = j0 - 4 + v; gj = gj < 0 ? 0 : (gj > 255 ? 255 : gj);
        Bf[p] = img[gi * W_ + gj] / sc;
    }
    __syncthreads();

    // loop-invariant per-slot state
    int bi_[11], mk_[11], go_[11];
    float xn0_[11], xn1_[11];
    #pragma unroll
    for (int k = 0; k < 11; k++) {
        int p = t + 256 * k;
        bool valid = p < NPAIRS;           // slot 10: only t<32
        int pp = valid ? p : 0;
        int u = pp / NPR, v0 = 2 * (pp - u * NPR);
        int bi = (u + 1) * TSB + v0;
        int gi = i0 - 4 + u, gj0 = j0 - 4 + v0;   // gj0 always even
        bool mn = valid && gi >= 0 && gi < 256 && gj0 >= 0 && gj0 <= 254;
        bool st = valid && u >= 4 && u < 68 && v0 >= 4 && v0 < 68;
        int mk = (mn ? 1 : 0)
               | ((mn && gj0 == 0)   ? 2  : 0)
               | ((mn && gj0 == 254) ? 4  : 0)
               | ((mn && gi  == 0)   ? 8  : 0)
               | ((mn && gi  == 255) ? 16 : 0)
               | (st ? 32 : 0);
        bi_[k] = bi; mk_[k] = mk; go_[k] = gi * W_ + gj0;
        xn0_[k] = Bf[bi]; xn1_[k] = Bf[bi + 1];
    }

    float n0_[11], n1_[11];

    #pragma unroll 1
    for (int view = 0; view < 4; view++) {
        const float lam = (view == 0) ? l0 : (view == 1) ? l1 : (view == 2) ? l2 : l3;
        const float del = (view == 0) ? e0 : (view == 1) ? e1 : (view == 2) ? e2 : e3;

        #pragma unroll 1
        for (int it = 0; it < 3; it++) {
            #pragma unroll
            for (int k = 0; k < 11; k++) {
                const int bi = bi_[k];
                const float2 self = *(const float2*)&Bf[bi];
                const float2 up   = *(const float2*)&Bf[bi - TSB];
                const float2 dn   = *(const float2*)&Bf[bi + TSB];
                const float lft = Bf[bi - 1], rgt = Bf[bi + 2];
                const float a0 = self.x, a1 = self.y;
                const float m    = g_of(a1 - a0, del);
                const float gxl0 = g_of(a0 - lft, del);
                const float gxr1 = g_of(rgt - a1, del);
                const float gyu0 = g_of(a0 - up.x, del);
                const float gyu1 = g_of(a1 - up.y, del);
                const float gyd0 = g_of(dn.x - a0, del);
                const float gyd1 = g_of(dn.y - a1, del);
                const float dv0 = (m - gxl0) + (gyd0 - gyu0);
                const float dv1 = (gxr1 - m) + (gyd1 - gyu1);
                const float q0 = fmaf(-lam, dv0, a0 - xn0_[k]);
                const float q1 = fmaf(-lam, dv1, a1 - xn1_[k]);
                n0_[k] = fmaf(-0.2f, q0, a0);
                n1_[k] = fmaf(-0.2f, q1, a1);
            }
            __syncthreads();   // all snapshot reads done
            if (it < 2) {
                #pragma unroll
                for (int k = 0; k < 11; k++) {
                    if (mk_[k] & 1) {
                        const int bi = bi_[k];
                        float2 pr; pr.x = n0_[k]; pr.y = n1_[k];
                        *(float2*)&Bf[bi] = pr;
                        if (mk_[k] & 2)  Bf[bi - 1] = pr.x;         // left image mirror
                        if (mk_[k] & 4)  Bf[bi + 2] = pr.y;         // right image mirror
                        if (mk_[k] & 8)  *(float2*)&Bf[bi - TSB] = pr;  // top mirror
                        if (mk_[k] & 16) *(float2*)&Bf[bi + TSB] = pr;  // bottom mirror
                    }
                }
                __syncthreads();
            }
        }

        // restore xn into LDS for the next view (out-of-image halo never touched)
        if (view < 3) {
            #pragma unroll
            for (int k = 0; k < 11; k++) {
                if (mk_[k] & 1) {
                    const int bi = bi_[k];
                    float2 pr; pr.x = xn0_[k]; pr.y = xn1_[k];
                    *(float2*)&Bf[bi] = pr;
                    if (mk_[k] & 2)  Bf[bi - 1] = pr.x;
                    if (mk_[k] & 4)  Bf[bi + 2] = pr.y;
                    if (mk_[k] & 8)  *(float2*)&Bf[bi - TSB] = pr;
                    if (mk_[k] & 16) *(float2*)&Bf[bi + TSB] = pr;
                }
            }
        }

        // store center 64x64
        float* vout = views + (size_t)view * TOT_ + (size_t)bc * HW_;
        #pragma unroll
        for (int k = 0; k < 11; k++) {
            if (mk_[k] & 32) {
                float2 o; o.x = n0_[k] * sc; o.y = n1_[k] * sc;
                *reinterpret_cast<float2*>(&vout[go_[k]]) = o;
            }
        }
        if (view < 3) __syncthreads();
    }
}

// ---------------- K3: per-pixel med/dev/mad -> deterministic partials ----------------
__global__ __launch_bounds__(256) void k_stats(const float* __restrict__ x,
                                               const float* __restrict__ views,
                                               float* __restrict__ pmad,
                                               float* __restrict__ pdev) {
    int t = threadIdx.x, chunk = blockIdx.x, b = blockIdx.y;
    size_t base = (size_t)b*CHW_ + (size_t)chunk*4096;
    float am = 0.f, ad = 0.f;
    for (int i = 0; i < 16; i++) {
        size_t idx = base + i*256 + t;
        float s0 = x[idx];
        float s1 = views[idx];
        float s2 = views[(size_t)TOT_ + idx];
        float s3 = views[2ull*TOT_ + idx];
        float s4 = views[3ull*TOT_ + idx];
        float med = median5(s0, s1, s2, s3, s4);
        float d0 = fabsf(s0-med), d1 = fabsf(s1-med), d2 = fabsf(s2-med),
              d3 = fabsf(s3-med), d4 = fabsf(s4-med);
        float mad = median5(d0, d1, d2, d3, d4);
        am += mad;
        ad += d0 + d1 + d2 + d3 + d4;
    }
    __shared__ float r[256];
    r[t] = am; __syncthreads();
    for (int off = 128; off > 0; off >>= 1) { if (t < off) r[t] += r[t+off]; __syncthreads(); }
    if (t == 0) pmad[b*48 + chunk] = r[0];
    __syncthreads();
    r[t] = ad; __syncthreads();
    for (int off = 128; off > 0; off >>= 1) { if (t < off) r[t] += r[t+off]; __syncthreads(); }
    if (t == 0) pdev[b*48 + chunk] = r[0];
}

// ---------------- K4: finalize scalars (mad mean, beta) ----------------
__global__ __launch_bounds__(256) void k_final(const float* __restrict__ pmad,
                                               const float* __restrict__ pdev,
                                               float* __restrict__ meanp,
                                               float* __restrict__ out_beta) {
    __shared__ float r[256];
    int t = threadIdx.x;
    float s = 0.f;
    for (int j = t; j < 1536; j += 256) s += pmad[j];
    r[t] = s; __syncthreads();
    for (int off = 128; off > 0; off >>= 1) { if (t < off) r[t] += r[t+off]; __syncthreads(); }
    if (t == 0) meanp[0] = r[0] / (float)TOT_;
    if (t < 32) {
        float sd = 0.f;
        for (int j = 0; j < 48; j++) sd += pdev[t*48 + j];
        float D = sd / (5.0f * (float)CHW_);
        float z = (D - 0.02f) / 0.01f;
        out_beta[t] = 1.0f / (1.0f + __expf(-z));
    }
}

// ---------------- K5: fusion ----------------
__global__ __launch_bounds__(256) void k_fuse(const float* __restrict__ x,
                                              const float* __restrict__ views,
                                              const float* __restrict__ meanp,
                                              float* __restrict__ out) {
    int t = threadIdx.x;
    size_t base = (size_t)blockIdx.x * 4096;
    float floorv = 0.1f * meanp[0];
    for (int i = 0; i < 16; i++) {
        size_t idx = base + i*256 + t;
        float s0 = x[idx];
        float s1 = views[idx];
        float s2 = views[(size_t)TOT_ + idx];
        float s3 = views[2ull*TOT_ + idx];
        float s4 = views[3ull*TOT_ + idx];
        float med = median5(s0, s1, s2, s3, s4);
        float d0 = fabsf(s0-med), d1 = fabsf(s1-med), d2 = fabsf(s2-med),
              d3 = fabsf(s3-med), d4 = fabsf(s4-med);
        float mad = median5(d0, d1, d2, d3, d4);
        float madf = fmaxf(mad, floorv);
        float inv = 1.0f / (2.0f * madf);
        float w0 = __expf(-d0*inv), w1 = __expf(-d1*inv), w2 = __expf(-d2*inv),
              w3 = __expf(-d3*inv), w4 = __expf(-d4*inv);
        float num = w0*s0 + w1*s1 + w2*s2 + w3*s3 + w4*s4;
        float den = w0 + w1 + w2 + w3 + w4 + 1e-8f;
        out[idx] = num / den;
    }
}

extern "C" void kernel_launch(void* const* d_in, const int* in_sizes, int n_in,
                              void* d_out, int out_size, void* d_ws, size_t ws_size,
                              hipStream_t stream) {
    const float* x = (const float*)d_in[0];
    float* out = (float*)d_out;
    char* ws = (char*)d_ws;
    float*    views = (float*)(ws + VIEWS_OFF_B);
    unsigned* ghist = (unsigned*)(ws + HIST_OFF_B);
    unsigned* state = (unsigned*)(ws + STATE_OFF_B);
    float*    scale = (float*)(ws + SCALE_OFF_B);
    float*    pmad  = (float*)(ws + PMAD_OFF_B);
    float*    pdev  = (float*)(ws + PDEV_OFF_B);
    float*    meanp = (float*)(ws + MEAN_OFF_B);

    // param sets: replicate np.random.RandomState(0).uniform(-.1,.1) draws
    const double s4[4] = {0.5488135039273248, 0.7151893663724195,
                          0.6027633760716439, 0.5448831829968969};
    float lam[4], del[4];
    for (int i = 0; i < 4; i++) {
        double lb  = 0.025 + (0.075 - 0.025) * (double)i / 3.0;
        double jit = -0.1 + 0.2 * s4[i];
        double li  = lb * (1.0 + jit);
        if (li < 0.0) li = 0.0;
        double di  = 0.01 * sqrt(li / (0.05 + 1e-8));
        lam[i] = (float)li; del[i] = (float)di;
    }

    hipMemsetAsync(ghist, 0, 32*2048*4, stream);
    k_init<<<1, 32, 0, stream>>>(state);

    // 3-pass radix select: bits [31:21], [20:10], [10:0]
    k_hist  <<<dim3(48,32), 256, 0, stream>>>(x, ghist, state, 0u,          21);
    k_select<<<32,          256, 0, stream>>>(ghist, state, scale, 21, 0);
    k_hist  <<<dim3(48,32), 256, 0, stream>>>(x, ghist, state, 0xFFE00000u, 10);
    k_select<<<32,          256, 0, stream>>>(ghist, state, scale, 10, 0);
    k_hist  <<<dim3(48,32), 256, 0, stream>>>(x, ghist, state, 0xFFFFFC00u, 0);
    k_select<<<32,          256, 0, stream>>>(ghist, state, scale, 0, 1);

    k_views<<<dim3(16,96), 256, 0, stream>>>(x, views, scale,
                                             lam[0], lam[1], lam[2], lam[3],
                                             del[0], del[1], del[2], del[3]);
    k_stats<<<dim3(48,32), 256, 0, stream>>>(x, views, pmad, pdev);
    k_final<<<1,           256, 0, stream>>>(pmad, pdev, meanp, out + TOT_);
    k_fuse <<<1536,        256, 0, stream>>>(x, views, meanp, out);
    (void)in_sizes; (void)n_in; (void)out_size; (void)ws_size;
}